// Round 2
// baseline (475.429 us; speedup 1.0000x reference)
//
#include <hip/hip_runtime.h>

#define HH 64
#define VV 50257
#define BB 32
#define LL 4096

constexpr float LN_EPS_F = 1e-5f;
constexpr float DELTA_EPS_F = 1e-6f;

constexpr int CS = 64;       // chunk size (steps per chunk)
constexpr int NG = LL / CS;  // 64 chunks per batch

// ---------------- DPP wave reduction (sum of 64 lanes -> lane 63) ----------------
template <int CTRL>
__device__ __forceinline__ float dpp_add(float x) {
  int t = __builtin_amdgcn_update_dpp(0, __float_as_int(x), CTRL, 0xF, 0xF, true);
  return x + __int_as_float(t);
}

__device__ __forceinline__ float wave_sum_lane63(float x) {
  x = dpp_add<0x111>(x);  // row_shr:1
  x = dpp_add<0x112>(x);  // row_shr:2
  x = dpp_add<0x114>(x);  // row_shr:4
  x = dpp_add<0x118>(x);  // row_shr:8
  x = dpp_add<0x142>(x);  // row_bcast:15
  x = dpp_add<0x143>(x);  // row_bcast:31
  return x;               // lane 63 holds the full sum
}

__device__ __forceinline__ float readlane_f(float x, int lane) {
  return __int_as_float(__builtin_amdgcn_readlane(__float_as_int(x), lane));
}

// ---------------- Kernel 0: transpose w1 -> w1T[j][h] ----------------
__global__ __launch_bounds__(256) void prep_kernel(const float* __restrict__ w1,
                                                   float* __restrict__ w1T) {
  int i = blockIdx.x * 256 + threadIdx.x;  // 8192 elements
  int h = i >> 7, j = i & 127;             // w1[h][j], h<64, j<128
  w1T[j * HH + h] = w1[i];
}

// ---------------- Kernel 1: encoder — weights via uniform scalar loads ----------
// one thread per token; e[] and acc a[] live in VGPRs; w columns/rows are
// wave-uniform reads -> SGPR s_load batches (no LDS traffic at all).
__global__ __launch_bounds__(256) void encoder_kernel(
    const int* __restrict__ seq, const float* __restrict__ embed,
    const float* __restrict__ w1T, const float* __restrict__ b1,
    const float* __restrict__ w2, const float* __restrict__ b2,
    const float* __restrict__ ln_g, const float* __restrict__ ln_b,
    float* __restrict__ h_all, float* __restrict__ beta) {
  int n = blockIdx.x * 256 + threadIdx.x;  // token index in [0, B*L)
  int s = seq[n];

  float e[HH];
  {
    const float4* ep = reinterpret_cast<const float4*>(embed + (size_t)s * HH);
#pragma unroll
    for (int i = 0; i < 16; ++i) {
      float4 v = ep[i];
      e[4 * i + 0] = v.x; e[4 * i + 1] = v.y;
      e[4 * i + 2] = v.z; e[4 * i + 3] = v.w;
    }
  }

  float a[HH];
#pragma unroll
  for (int h = 0; h < HH; ++h) a[h] = b2[h];  // uniform -> s_load

#pragma unroll 2
  for (int jj = 0; jj < 2 * HH; ++jj) {
    const float* wc = w1T + jj * HH;  // uniform column of w1
    float h0 = 0.f, h1 = 0.f, h2 = 0.f, h3 = 0.f;
#pragma unroll
    for (int h = 0; h < HH; h += 4) {
      h0 = fmaf(e[h + 0], wc[h + 0], h0);
      h1 = fmaf(e[h + 1], wc[h + 1], h1);
      h2 = fmaf(e[h + 2], wc[h + 2], h2);
      h3 = fmaf(e[h + 3], wc[h + 3], h3);
    }
    float hj = fmaxf((h0 + h1) + (h2 + h3) + b1[jj], 0.f);
    const float* wr = w2 + jj * HH;  // uniform row of w2
#pragma unroll
    for (int h = 0; h < HH; ++h) a[h] = fmaf(hj, wr[h], a[h]);
  }

  // x = e + f ; LayerNorm
  float sum = 0.f;
#pragma unroll
  for (int h = 0; h < HH; ++h) { a[h] += e[h]; sum += a[h]; }
  float mu = sum * (1.f / HH);
  float vs = 0.f;
#pragma unroll
  for (int h = 0; h < HH; ++h) { float dx = a[h] - mu; vs = fmaf(dx, dx, vs); }
  float rstd = rsqrtf(vs * (1.f / HH) + LN_EPS_F);

  float ss = 0.f;
  float4* hp = reinterpret_cast<float4*>(h_all + (size_t)n * HH);
#pragma unroll
  for (int i = 0; i < 16; ++i) {
    float4 o;
    o.x = fmaf((a[4 * i + 0] - mu) * rstd, ln_g[4 * i + 0], ln_b[4 * i + 0]);
    o.y = fmaf((a[4 * i + 1] - mu) * rstd, ln_g[4 * i + 1], ln_b[4 * i + 1]);
    o.z = fmaf((a[4 * i + 2] - mu) * rstd, ln_g[4 * i + 2], ln_b[4 * i + 2]);
    o.w = fmaf((a[4 * i + 3] - mu) * rstd, ln_g[4 * i + 3], ln_b[4 * i + 3]);
    ss = fmaf(o.x, o.x, ss); ss = fmaf(o.y, o.y, ss);
    ss = fmaf(o.z, o.z, ss); ss = fmaf(o.w, o.w, ss);
    hp[i] = o;
  }
  beta[n] = 1.f / (ss + DELTA_EPS_F);  // beta_t = 1/(k.k + eps)
}

// ---------------- Kernel 2 (phase 1): per-chunk transform matrices ----------------
// A_c = A_lo * A_{lo+1} * ... * A_hi,  A_t = I - beta_t k_t k_t^T
// One wave per (b, c); lane = column. Per step: d = k . A[:,lane] (128 indep FMAs).
__global__ __launch_bounds__(64) void chunk_mat_kernel(
    const float* __restrict__ h_all, const float* __restrict__ beta,
    float* __restrict__ A_g) {
  int c = blockIdx.x, b = blockIdx.y, lane = threadIdx.x;
  const float* hb = h_all + (size_t)b * LL * HH;
  const float* betab = beta + (size_t)b * LL;

  float A[HH];
#pragma unroll
  for (int h = 0; h < HH; ++h) A[h] = (h == lane) ? 1.f : 0.f;

  int hi = c * CS + CS - 1, lo = c * CS;
#pragma unroll 2
  for (int t = hi; t >= lo; --t) {
    const float* kp = hb + (size_t)t * HH;  // uniform -> scalar loads
    float d0 = 0.f, d1 = 0.f, d2 = 0.f, d3 = 0.f;
#pragma unroll
    for (int h = 0; h < HH; h += 4) {
      d0 = fmaf(kp[h + 0], A[h + 0], d0);
      d1 = fmaf(kp[h + 1], A[h + 1], d1);
      d2 = fmaf(kp[h + 2], A[h + 2], d2);
      d3 = fmaf(kp[h + 3], A[h + 3], d3);
    }
    float d = (d0 + d1) + (d2 + d3);
    if (t == LL - 1) d = 0.f;  // t=L-1 is q's slot, not a key (uniform branch)
    float bd = -betab[t] * d;
#pragma unroll
    for (int h = 0; h < HH; ++h) A[h] = fmaf(bd, kp[h], A[h]);
  }

  float* Ag = A_g + ((size_t)b * NG + c) * HH * HH;
#pragma unroll
  for (int h = 0; h < HH; ++h) Ag[(size_t)h * HH + lane] = A[h];  // coalesced rows
}

// ---------------- Kernel 3 (phase 2): chunk-boundary propagation ----------------
// Q_{NG-1} = q; store Q_c then Q_{c-1} = A_c Q_c. One wave per batch; lane = row.
__global__ __launch_bounds__(64) void boundary_kernel(
    const float* __restrict__ h_all, const float* __restrict__ A_g,
    const int* __restrict__ read_pos_p, float* __restrict__ Qg) {
  int b = blockIdx.x, lane = threadIdx.x;
  int rpv = read_pos_p[0];
  int pos = rpv < 0 ? rpv + LL : rpv;

  float Q = h_all[((size_t)b * LL + pos) * HH + lane];

  float4 cur[16], nxt[16];
  {
    const float4* rp4 = reinterpret_cast<const float4*>(
        A_g + ((size_t)b * NG + (NG - 1)) * HH * HH + (size_t)lane * HH);
#pragma unroll
    for (int i = 0; i < 16; ++i) cur[i] = rp4[i];
  }

#pragma unroll 1
  for (int c = NG - 1; c >= 0; --c) {
    if (c > 0) {  // prefetch next chunk's row while we compute
      const float4* rp4 = reinterpret_cast<const float4*>(
          A_g + ((size_t)b * NG + (c - 1)) * HH * HH + (size_t)lane * HH);
#pragma unroll
      for (int i = 0; i < 16; ++i) nxt[i] = rp4[i];
    }
    Qg[((size_t)b * NG + c) * HH + lane] = Q;
    float a0 = 0.f, a1 = 0.f, a2 = 0.f, a3 = 0.f;
#pragma unroll
    for (int i = 0; i < 16; ++i) {
      a0 = fmaf(readlane_f(Q, 4 * i + 0), cur[i].x, a0);
      a1 = fmaf(readlane_f(Q, 4 * i + 1), cur[i].y, a1);
      a2 = fmaf(readlane_f(Q, 4 * i + 2), cur[i].z, a2);
      a3 = fmaf(readlane_f(Q, 4 * i + 3), cur[i].w, a3);
    }
    Q = (a0 + a1) + (a2 + a3);
#pragma unroll
    for (int i = 0; i < 16; ++i) cur[i] = nxt[i];
  }
}

// ---------------- Kernel 4 (phase 3): parallel within-chunk r accumulation -------
// With Q_c known, run the O(H) vector scan inside each chunk; r_c -> rc[b][c][:].
__global__ __launch_bounds__(64) void chunk_scan_kernel(
    const float* __restrict__ h_all, const float* __restrict__ beta,
    const float* __restrict__ Qg, float* __restrict__ rc) {
  int c = blockIdx.x, b = blockIdx.y, j = threadIdx.x;
  const float* hb = h_all + (size_t)b * LL * HH;
  const float* betab = beta + (size_t)b * LL;

  float P = Qg[((size_t)b * NG + c) * HH + j];
  float r = 0.f;

  float kk[CS];
#pragma unroll
  for (int i = 0; i < CS; ++i) kk[i] = hb[((size_t)(c * CS + i)) * HH + j];
  float bv = betab[c * CS + j];  // lane j holds beta_{cCS+j}

  bool last = (c == NG - 1);
#pragma unroll
  for (int i = CS - 1; i >= 0; --i) {
    float k = kk[i];
    float bt = readlane_f(bv, i);
    float m = k * P;
    float s = wave_sum_lane63(m);
    float d = readlane_f(s, 63);
    if (i == CS - 1 && last) d = 0.f;  // mask t = L-1
    r = fmaf(d, k, r);
    P = fmaf(-(bt * d), k, P);
  }
  rc[((size_t)b * NG + c) * HH + j] = r;
}

// ---------------- Kernel 5: combine r over chunks, y = r @ rp_w + rp_b ----------
__global__ __launch_bounds__(64) void combine_kernel(
    const float* __restrict__ rc, const float* __restrict__ rp_w,
    const float* __restrict__ rp_b, float* __restrict__ yv) {
  int b = blockIdx.x, j = threadIdx.x;
  float r = 0.f;
#pragma unroll 8
  for (int cc = 0; cc < NG; ++cc) r += rc[((size_t)b * NG + cc) * HH + j];
  __shared__ float rs[HH];
  rs[j] = r;
  __syncthreads();
  float yj = rp_b[j];
#pragma unroll
  for (int h = 0; h < HH; ++h) yj = fmaf(rs[h], rp_w[h * HH + j], yj);
  yv[b * HH + j] = yj;
}

// ---------------- Kernel 6: output GEMM ----------------
__global__ __launch_bounds__(256) void out_kernel(
    const float* __restrict__ yv, const float* __restrict__ out_w,
    const float* __restrict__ out_b, float* __restrict__ out) {
  __shared__ float ys[BB * HH];
  for (int i = threadIdx.x; i < BB * HH; i += 256) ys[i] = yv[i];
  __syncthreads();

  int v = blockIdx.x * 256 + threadIdx.x;
  if (v >= VV) return;

  float acc[BB];
  float ob = out_b[v];
#pragma unroll
  for (int b = 0; b < BB; ++b) acc[b] = ob;

  for (int h = 0; h < HH; ++h) {
    float w = out_w[(size_t)h * VV + v];
#pragma unroll
    for (int b = 0; b < BB; ++b) acc[b] = fmaf(ys[b * HH + h], w, acc[b]);
  }
#pragma unroll
  for (int b = 0; b < BB; ++b) out[(size_t)b * VV + v] = acc[b];
}

// ---------------- launch ----------------
extern "C" void kernel_launch(void* const* d_in, const int* in_sizes, int n_in,
                              void* d_out, int out_size, void* d_ws, size_t ws_size,
                              hipStream_t stream) {
  (void)in_sizes; (void)n_in; (void)out_size; (void)ws_size;
  const int*   seq   = (const int*)d_in[0];
  const int*   rp    = (const int*)d_in[1];
  const float* embed = (const float*)d_in[2];
  const float* w1    = (const float*)d_in[3];
  const float* b1    = (const float*)d_in[4];
  const float* w2    = (const float*)d_in[5];
  const float* b2    = (const float*)d_in[6];
  const float* ln_g  = (const float*)d_in[7];
  const float* ln_b  = (const float*)d_in[8];
  const float* rp_w  = (const float*)d_in[9];
  const float* rp_b  = (const float*)d_in[10];
  const float* out_w = (const float*)d_in[11];
  const float* out_b = (const float*)d_in[12];
  float* out = (float*)d_out;

  // workspace layout (~68.7 MB)
  float* h_all = (float*)d_ws;                               // B*L*H
  float* beta  = h_all + (size_t)BB * LL * HH;               // B*L
  float* A_g   = beta + (size_t)BB * LL;                     // B*NG*H*H
  float* Qg    = A_g + (size_t)BB * NG * HH * HH;            // B*NG*H
  float* rcv   = Qg + (size_t)BB * NG * HH;                  // B*NG*H
  float* yv    = rcv + (size_t)BB * NG * HH;                 // B*H
  float* w1T   = yv + (size_t)BB * HH;                       // 2H*H

  prep_kernel<<<32, 256, 0, stream>>>(w1, w1T);
  encoder_kernel<<<BB * LL / 256, 256, 0, stream>>>(seq, embed, w1T, b1, w2, b2,
                                                    ln_g, ln_b, h_all, beta);
  chunk_mat_kernel<<<dim3(NG, BB), 64, 0, stream>>>(h_all, beta, A_g);
  boundary_kernel<<<BB, 64, 0, stream>>>(h_all, A_g, rp, Qg);
  chunk_scan_kernel<<<dim3(NG, BB), 64, 0, stream>>>(h_all, beta, Qg, rcv);
  combine_kernel<<<BB, 64, 0, stream>>>(rcv, rp_w, rp_b, yv);
  out_kernel<<<(VV + 255) / 256, 256, 0, stream>>>(yv, out_w, out_b, out);
}